// Round 1
// baseline (117.751 us; speedup 1.0000x reference)
//
#include <hip/hip_runtime.h>
#include <hip/hip_bf16.h>

// out[b,n] = sum_k x[b,k] * weight[indices[n],k]
// M=64 (batch), N=4403 (remained), K=4096 (hidden), fp32 in/out.
// Strategy: gathered GEMM via mfma_f32_16x16x32_bf16, fp32 loads converted
// to bf16 in-register. No LDS; fragments are contiguous k-runs in global.

#define HIDDEN 4096
#define KSTEPS (HIDDEN / 32)

using short8 = __attribute__((ext_vector_type(8))) short;   // 8 bf16 in 4 VGPRs
using f32x4  = __attribute__((ext_vector_type(4))) float;

__device__ inline short f2bf(float f) {
    __bf16 h = (__bf16)f;                 // compiler pairs into v_cvt_pk_bf16_f32
    return __builtin_bit_cast(short, h);
}

__global__ __launch_bounds__(256) void up_gather_gemm(
    const float* __restrict__ x,        // [B, 4096]
    const float* __restrict__ weight,   // [11008, 4096]
    const int*   __restrict__ indices,  // [R]
    float*       __restrict__ out,      // [B, R]
    int R)
{
    const int lane  = threadIdx.x & 63;
    const int wave  = threadIdx.x >> 6;      // 0..3 -> M-tile (16 batch rows each)
    const int nb    = blockIdx.x;            // N-tile of 16 gathered rows
    const int nl    = lane & 15;             // fragment row/col index
    const int kg    = lane >> 4;             // k-group 0..3 (8 elements each)

    const int n      = nb * 16 + nl;
    const int n_safe = n < R ? n : R - 1;
    const int row    = indices[n_safe];

    const float* wptr = weight + (size_t)row * HIDDEN + kg * 8;
    const float* xptr = x + (size_t)(wave * 16 + nl) * HIDDEN + kg * 8;

    f32x4 acc = {0.f, 0.f, 0.f, 0.f};

#pragma unroll 4
    for (int ks = 0; ks < KSTEPS; ++ks) {
        f32x4 w0 = *(const f32x4*)(wptr);
        f32x4 w1 = *(const f32x4*)(wptr + 4);
        f32x4 x0 = *(const f32x4*)(xptr);
        f32x4 x1 = *(const f32x4*)(xptr + 4);
        wptr += 32; xptr += 32;

        short8 a, b;
        a[0] = f2bf(x0[0]); a[1] = f2bf(x0[1]); a[2] = f2bf(x0[2]); a[3] = f2bf(x0[3]);
        a[4] = f2bf(x1[0]); a[5] = f2bf(x1[1]); a[6] = f2bf(x1[2]); a[7] = f2bf(x1[3]);
        b[0] = f2bf(w0[0]); b[1] = f2bf(w0[1]); b[2] = f2bf(w0[2]); b[3] = f2bf(w0[3]);
        b[4] = f2bf(w1[0]); b[5] = f2bf(w1[1]); b[6] = f2bf(w1[2]); b[7] = f2bf(w1[3]);

        acc = __builtin_amdgcn_mfma_f32_16x16x32_bf16(a, b, acc, 0, 0, 0);
    }

    // C/D layout: col = lane&15 (n), row = (lane>>4)*4 + r (batch within M-tile)
    if (n < R) {
#pragma unroll
        for (int r = 0; r < 4; ++r) {
            const int brow = wave * 16 + kg * 4 + r;
            out[(size_t)brow * R + n] = acc[r];
        }
    }
}

extern "C" void kernel_launch(void* const* d_in, const int* in_sizes, int n_in,
                              void* d_out, int out_size, void* d_ws, size_t ws_size,
                              hipStream_t stream) {
    const float* x       = (const float*)d_in[0];
    const float* weight  = (const float*)d_in[1];
    const int*   indices = (const int*)d_in[2];
    float*       out     = (float*)d_out;

    const int R = in_sizes[2];                 // 4403
    const int nblocks = (R + 15) / 16;         // 276

    up_gather_gemm<<<dim3(nblocks), dim3(256), 0, stream>>>(x, weight, indices, out, R);
}

// Round 2
// 66.736 us; speedup vs baseline: 1.7644x; 1.7644x over previous
//
#include <hip/hip_runtime.h>
#include <hip/hip_bf16.h>

// out[b,n] = sum_k x[b,k] * weight[indices[n],k]
// M=64, N=4403, K=4096, fp32 in/out. Gathered GEMM via mfma_f32_16x16x32_bf16.
// R2: K-split 8x across blockIdx.y (latency hiding: 4416 waves vs 1104),
// NT=32 per block (halves duplicated x traffic), fp32 atomics to combine
// K-partials, memset-on-stream for zero init.

#define HIDDEN 4096
#define KSPLIT 8
#define KCHUNK (HIDDEN / KSPLIT)   // 512
#define ITERS  (KCHUNK / 32)       // 16 MFMA steps per wave

using short8 = __attribute__((ext_vector_type(8))) short;   // 8 bf16
using f32x4  = __attribute__((ext_vector_type(4))) float;

__device__ inline short f2bf(float f) {
    __bf16 h = (__bf16)f;                 // pairs into v_cvt_pk_bf16_f32
    return __builtin_bit_cast(short, h);
}

__device__ inline short8 cvt8(const f32x4& lo, const f32x4& hi) {
    short8 r;
    r[0] = f2bf(lo[0]); r[1] = f2bf(lo[1]); r[2] = f2bf(lo[2]); r[3] = f2bf(lo[3]);
    r[4] = f2bf(hi[0]); r[5] = f2bf(hi[1]); r[6] = f2bf(hi[2]); r[7] = f2bf(hi[3]);
    return r;
}

__global__ __launch_bounds__(256) void up_gather_gemm(
    const float* __restrict__ x,        // [64, 4096]
    const float* __restrict__ weight,   // [11008, 4096]
    const int*   __restrict__ indices,  // [R]
    float*       __restrict__ out,      // [64, R]
    int R)
{
    const int lane = threadIdx.x & 63;
    const int wave = threadIdx.x >> 6;       // 0..3 -> M-tile (16 batch rows)
    const int nb   = blockIdx.x;             // N-tile of 32 gathered rows
    const int kb   = blockIdx.y;             // K-chunk of 512
    const int nl   = lane & 15;
    const int kg   = lane >> 4;              // k-group 0..3

    const int n0 = nb * 32 + nl;
    const int n1 = n0 + 16;
    const int r0 = indices[n0 < R ? n0 : R - 1];
    const int r1 = indices[n1 < R ? n1 : R - 1];

    const int kbase = kb * KCHUNK + kg * 8;
    const float* wp0 = weight + (size_t)r0 * HIDDEN + kbase;
    const float* wp1 = weight + (size_t)r1 * HIDDEN + kbase;
    const float* xp  = x + (size_t)(wave * 16 + nl) * HIDDEN + kbase;

    f32x4 acc0 = {0.f, 0.f, 0.f, 0.f};
    f32x4 acc1 = {0.f, 0.f, 0.f, 0.f};

#pragma unroll 4
    for (int it = 0; it < ITERS; ++it) {
        f32x4 xa = *(const f32x4*)(xp);
        f32x4 xb = *(const f32x4*)(xp + 4);
        f32x4 w0a = *(const f32x4*)(wp0);
        f32x4 w0b = *(const f32x4*)(wp0 + 4);
        f32x4 w1a = *(const f32x4*)(wp1);
        f32x4 w1b = *(const f32x4*)(wp1 + 4);
        xp += 32; wp0 += 32; wp1 += 32;

        short8 a  = cvt8(xa, xb);
        short8 b0 = cvt8(w0a, w0b);
        short8 b1 = cvt8(w1a, w1b);

        acc0 = __builtin_amdgcn_mfma_f32_16x16x32_bf16(a, b0, acc0, 0, 0, 0);
        acc1 = __builtin_amdgcn_mfma_f32_16x16x32_bf16(a, b1, acc1, 0, 0, 0);
    }

    // C/D: col = lane&15 (n), row = kg*4 + r (batch within this wave's M-tile)
#pragma unroll
    for (int r = 0; r < 4; ++r) {
        const int brow = wave * 16 + kg * 4 + r;
        if (n0 < R) unsafeAtomicAdd(&out[(size_t)brow * R + n0], acc0[r]);
        if (n1 < R) unsafeAtomicAdd(&out[(size_t)brow * R + n1], acc1[r]);
    }
}

extern "C" void kernel_launch(void* const* d_in, const int* in_sizes, int n_in,
                              void* d_out, int out_size, void* d_ws, size_t ws_size,
                              hipStream_t stream) {
    const float* x       = (const float*)d_in[0];
    const float* weight  = (const float*)d_in[1];
    const int*   indices = (const int*)d_in[2];
    float*       out     = (float*)d_out;

    const int R = in_sizes[2];                 // 4403
    const int nb = (R + 31) / 32;              // 138

    hipMemsetAsync(out, 0, (size_t)out_size * sizeof(float), stream);
    up_gather_gemm<<<dim3(nb, KSPLIT), dim3(256), 0, stream>>>(x, weight, indices, out, R);
}

// Round 3
// 63.587 us; speedup vs baseline: 1.8518x; 1.0495x over previous
//
#include <hip/hip_runtime.h>
#include <hip/hip_bf16.h>

// out[b,n] = sum_k x[b,k] * weight[indices[n],k]
// M=64, N=4403, K=4096, fp32 in/out. Gathered GEMM via mfma_f32_16x16x32_bf16.
// R3: K-split 8x -> plain stores of partials into d_ws (no memset, no atomics;
// R2's hipMemsetAsync became a ~100us small-grid fill kernel in the graph),
// then a float4 reduction kernel sums the 8 partials into d_out.

#define HIDDEN 4096
#define KSPLIT 8
#define KCHUNK (HIDDEN / KSPLIT)   // 512
#define ITERS  (KCHUNK / 32)       // 16 MFMA steps per wave
#define BATCH  64

using short8 = __attribute__((ext_vector_type(8))) short;   // 8 bf16
using f32x4  = __attribute__((ext_vector_type(4))) float;

__device__ inline short f2bf(float f) {
    __bf16 h = (__bf16)f;                 // pairs into v_cvt_pk_bf16_f32
    return __builtin_bit_cast(short, h);
}

__device__ inline short8 cvt8(const f32x4& lo, const f32x4& hi) {
    short8 r;
    r[0] = f2bf(lo[0]); r[1] = f2bf(lo[1]); r[2] = f2bf(lo[2]); r[3] = f2bf(lo[3]);
    r[4] = f2bf(hi[0]); r[5] = f2bf(hi[1]); r[6] = f2bf(hi[2]); r[7] = f2bf(hi[3]);
    return r;
}

__global__ __launch_bounds__(256) void up_gather_gemm(
    const float* __restrict__ x,        // [64, 4096]
    const float* __restrict__ weight,   // [11008, 4096]
    const int*   __restrict__ indices,  // [R]
    float*       __restrict__ ws,       // [KSPLIT, 64, R] partials
    int R)
{
    const int lane = threadIdx.x & 63;
    const int wave = threadIdx.x >> 6;       // 0..3 -> M-tile (16 batch rows)
    const int nb   = blockIdx.x;             // N-tile of 32 gathered rows
    const int kb   = blockIdx.y;             // K-chunk of 512
    const int nl   = lane & 15;
    const int kg   = lane >> 4;              // k-group 0..3

    const int n0 = nb * 32 + nl;
    const int n1 = n0 + 16;
    const int r0 = indices[n0 < R ? n0 : R - 1];
    const int r1 = indices[n1 < R ? n1 : R - 1];

    const int kbase = kb * KCHUNK + kg * 8;
    const float* wp0 = weight + (size_t)r0 * HIDDEN + kbase;
    const float* wp1 = weight + (size_t)r1 * HIDDEN + kbase;
    const float* xp  = x + (size_t)(wave * 16 + nl) * HIDDEN + kbase;

    f32x4 acc0 = {0.f, 0.f, 0.f, 0.f};
    f32x4 acc1 = {0.f, 0.f, 0.f, 0.f};

#pragma unroll 4
    for (int it = 0; it < ITERS; ++it) {
        f32x4 xa  = *(const f32x4*)(xp);
        f32x4 xb  = *(const f32x4*)(xp + 4);
        f32x4 w0a = *(const f32x4*)(wp0);
        f32x4 w0b = *(const f32x4*)(wp0 + 4);
        f32x4 w1a = *(const f32x4*)(wp1);
        f32x4 w1b = *(const f32x4*)(wp1 + 4);
        xp += 32; wp0 += 32; wp1 += 32;

        short8 a  = cvt8(xa, xb);
        short8 b0 = cvt8(w0a, w0b);
        short8 b1 = cvt8(w1a, w1b);

        acc0 = __builtin_amdgcn_mfma_f32_16x16x32_bf16(a, b0, acc0, 0, 0, 0);
        acc1 = __builtin_amdgcn_mfma_f32_16x16x32_bf16(a, b1, acc1, 0, 0, 0);
    }

    // C/D: col = lane&15 (n), row = kg*4 + r (batch within this wave's M-tile)
    float* part = ws + (size_t)kb * BATCH * R;
#pragma unroll
    for (int r = 0; r < 4; ++r) {
        const int brow = wave * 16 + kg * 4 + r;
        if (n0 < R) part[(size_t)brow * R + n0] = acc0[r];
        if (n1 < R) part[(size_t)brow * R + n1] = acc1[r];
    }
}

__global__ __launch_bounds__(256) void reduce_partials(
    const float* __restrict__ ws,   // [KSPLIT, 64*R]
    float*       __restrict__ out,  // [64*R]
    int n4, int stride4)            // n4 = 16*R, stride4 = 16*R
{
    const int i = blockIdx.x * blockDim.x + threadIdx.x;
    if (i >= n4) return;
    const f32x4* w = (const f32x4*)ws;
    f32x4 s = w[i];
#pragma unroll
    for (int kb = 1; kb < KSPLIT; ++kb) {
        f32x4 v = w[(size_t)kb * stride4 + i];
        s[0] += v[0]; s[1] += v[1]; s[2] += v[2]; s[3] += v[3];
    }
    ((f32x4*)out)[i] = s;
}

extern "C" void kernel_launch(void* const* d_in, const int* in_sizes, int n_in,
                              void* d_out, int out_size, void* d_ws, size_t ws_size,
                              hipStream_t stream) {
    const float* x       = (const float*)d_in[0];
    const float* weight  = (const float*)d_in[1];
    const int*   indices = (const int*)d_in[2];
    float*       out     = (float*)d_out;
    float*       ws      = (float*)d_ws;

    const int R  = in_sizes[2];                // 4403
    const int nb = (R + 31) / 32;              // 138

    up_gather_gemm<<<dim3(nb, KSPLIT), dim3(256), 0, stream>>>(x, weight, indices, ws, R);

    const int n4 = (BATCH * R) / 4;            // 64*R is divisible by 4
    reduce_partials<<<dim3((n4 + 255) / 256), dim3(256), 0, stream>>>(ws, out, n4, n4);
}

// Round 4
// 63.208 us; speedup vs baseline: 1.8629x; 1.0060x over previous
//
#include <hip/hip_runtime.h>
#include <hip/hip_bf16.h>

// out[b,n] = sum_k x[b,k] * weight[indices[n],k]
// M=64, N=4403, K=4096, fp32 in/out. Gathered GEMM via mfma_f32_16x16x32_bf16.
// R4: R3's GEMM ran at ~2100 cy/K-iter because VGPR_Count=40 -> compiler
// serialized load/cvt/mfma (no loads in flight). Fix: explicit depth-2
// register pipeline (12 dwordx4 loads in flight, forced live across MFMAs)
// + __launch_bounds__(256,4) (<=128 VGPR, 4 waves/EU residency).

#define HIDDEN 4096
#define KSPLIT 8
#define KCHUNK (HIDDEN / KSPLIT)   // 512
#define ITERS  (KCHUNK / 32)       // 16 MFMA steps per wave
#define BATCH  64

using short8 = __attribute__((ext_vector_type(8))) short;   // 8 bf16
using f32x4  = __attribute__((ext_vector_type(4))) float;

__device__ __forceinline__ short f2bf(float f) {
    __bf16 h = (__bf16)f;                 // pairs into v_cvt_pk_bf16_f32
    return __builtin_bit_cast(short, h);
}

__device__ __forceinline__ short8 cvt8(const f32x4& lo, const f32x4& hi) {
    short8 r;
    r[0] = f2bf(lo[0]); r[1] = f2bf(lo[1]); r[2] = f2bf(lo[2]); r[3] = f2bf(lo[3]);
    r[4] = f2bf(hi[0]); r[5] = f2bf(hi[1]); r[6] = f2bf(hi[2]); r[7] = f2bf(hi[3]);
    return r;
}

struct Frag { f32x4 x0, x1, a0, a1, b0, b1; };

__device__ __forceinline__ Frag load_frag(const float* xp, const float* wp0,
                                          const float* wp1) {
    Frag f;
    f.x0 = *(const f32x4*)(xp);
    f.x1 = *(const f32x4*)(xp + 4);
    f.a0 = *(const f32x4*)(wp0);
    f.a1 = *(const f32x4*)(wp0 + 4);
    f.b0 = *(const f32x4*)(wp1);
    f.b1 = *(const f32x4*)(wp1 + 4);
    return f;
}

__global__ __launch_bounds__(256, 4) void up_gather_gemm(
    const float* __restrict__ x,        // [64, 4096]
    const float* __restrict__ weight,   // [11008, 4096]
    const int*   __restrict__ indices,  // [R]
    float*       __restrict__ ws,       // [KSPLIT, 64, R] partials
    int R)
{
    const int lane = threadIdx.x & 63;
    const int wave = threadIdx.x >> 6;       // 0..3 -> M-tile (16 batch rows)
    const int nb   = blockIdx.x;             // N-tile of 32 gathered rows
    const int kb   = blockIdx.y;             // K-chunk of 512
    const int nl   = lane & 15;
    const int kg   = lane >> 4;              // k-group 0..3

    const int n0 = nb * 32 + nl;
    const int n1 = n0 + 16;
    const int r0 = indices[n0 < R ? n0 : R - 1];
    const int r1 = indices[n1 < R ? n1 : R - 1];

    const int kbase = kb * KCHUNK + kg * 8;
    const float* wp0 = weight + (size_t)r0 * HIDDEN + kbase;
    const float* wp1 = weight + (size_t)r1 * HIDDEN + kbase;
    const float* xp  = x + (size_t)(wave * 16 + nl) * HIDDEN + kbase;

    f32x4 acc0 = {0.f, 0.f, 0.f, 0.f};
    f32x4 acc1 = {0.f, 0.f, 0.f, 0.f};

    // depth-2 software pipeline: 12 dwordx4 loads in flight during compute
    Frag f0 = load_frag(xp, wp0, wp1);
    xp += 32; wp0 += 32; wp1 += 32;
    Frag f1 = load_frag(xp, wp0, wp1);
    xp += 32; wp0 += 32; wp1 += 32;

#pragma unroll
    for (int it = 0; it < ITERS - 2; ++it) {
        Frag fn = load_frag(xp, wp0, wp1);
        xp += 32; wp0 += 32; wp1 += 32;

        short8 a  = cvt8(f0.x0, f0.x1);
        short8 b0 = cvt8(f0.a0, f0.a1);
        short8 b1 = cvt8(f0.b0, f0.b1);
        acc0 = __builtin_amdgcn_mfma_f32_16x16x32_bf16(a, b0, acc0, 0, 0, 0);
        acc1 = __builtin_amdgcn_mfma_f32_16x16x32_bf16(a, b1, acc1, 0, 0, 0);

        f0 = f1; f1 = fn;
    }
    {
        short8 a  = cvt8(f0.x0, f0.x1);
        short8 b0 = cvt8(f0.a0, f0.a1);
        short8 b1 = cvt8(f0.b0, f0.b1);
        acc0 = __builtin_amdgcn_mfma_f32_16x16x32_bf16(a, b0, acc0, 0, 0, 0);
        acc1 = __builtin_amdgcn_mfma_f32_16x16x32_bf16(a, b1, acc1, 0, 0, 0);
    }
    {
        short8 a  = cvt8(f1.x0, f1.x1);
        short8 b0 = cvt8(f1.a0, f1.a1);
        short8 b1 = cvt8(f1.b0, f1.b1);
        acc0 = __builtin_amdgcn_mfma_f32_16x16x32_bf16(a, b0, acc0, 0, 0, 0);
        acc1 = __builtin_amdgcn_mfma_f32_16x16x32_bf16(a, b1, acc1, 0, 0, 0);
    }

    // C/D: col = lane&15 (n), row = kg*4 + r (batch within this wave's M-tile)
    float* part = ws + (size_t)kb * BATCH * R;
#pragma unroll
    for (int r = 0; r < 4; ++r) {
        const int brow = wave * 16 + kg * 4 + r;
        if (n0 < R) part[(size_t)brow * R + n0] = acc0[r];
        if (n1 < R) part[(size_t)brow * R + n1] = acc1[r];
    }
}

__global__ __launch_bounds__(256) void reduce_partials(
    const float* __restrict__ ws,   // [KSPLIT, 64*R]
    float*       __restrict__ out,  // [64*R]
    int n4, int stride4)
{
    const int i = blockIdx.x * blockDim.x + threadIdx.x;
    if (i >= n4) return;
    const f32x4* w = (const f32x4*)ws;
    f32x4 s = w[i];
#pragma unroll
    for (int kb = 1; kb < KSPLIT; ++kb) {
        f32x4 v = w[(size_t)kb * stride4 + i];
        s[0] += v[0]; s[1] += v[1]; s[2] += v[2]; s[3] += v[3];
    }
    ((f32x4*)out)[i] = s;
}

extern "C" void kernel_launch(void* const* d_in, const int* in_sizes, int n_in,
                              void* d_out, int out_size, void* d_ws, size_t ws_size,
                              hipStream_t stream) {
    const float* x       = (const float*)d_in[0];
    const float* weight  = (const float*)d_in[1];
    const int*   indices = (const int*)d_in[2];
    float*       out     = (float*)d_out;
    float*       ws      = (float*)d_ws;

    const int R  = in_sizes[2];                // 4403
    const int nb = (R + 31) / 32;              // 138

    up_gather_gemm<<<dim3(nb, KSPLIT), dim3(256), 0, stream>>>(x, weight, indices, ws, R);

    const int n4 = (BATCH * R) / 4;            // 64*R divisible by 4
    reduce_partials<<<dim3((n4 + 255) / 256), dim3(256), 0, stream>>>(ws, out, n4, n4);
}

// Round 5
// 32.642 us; speedup vs baseline: 3.6074x; 1.9364x over previous
//
#include <hip/hip_runtime.h>
#include <hip/hip_bf16.h>

// out[b,n] = sum_k x[b,k] * weight[indices[n],k]
// M=64, N=4403, K=4096, fp32 in/out.
// R5: R3/R4 were VALU-issue-bound (~50 VALU slots per 2 MFMAs: 6 scattered
// loads + 12 cvt + repack per iter, and all 4 waves duplicated the SAME
// weight fragments -> 4x traffic+cvt). Fix:
//   k0: x f32 -> bf16 once (ws)
//   k1: per block stage 64-row weight K-chunk in LDS as bf16 (cvt once,
//       XOR-swizzled vs 16-way bank conflict), K-loop = 1 glb load +
//       4 ds_read_b128 + 4 MFMA per K-step. KSPLIT=8 partials into ws.
//   k2: reduce 8 partials -> out.

#define HIDDEN 4096
#define KSPLIT 8
#define KCHUNK (HIDDEN / KSPLIT)   // 512
#define KSTEPS (KCHUNK / 32)       // 16
#define BATCH  64
#define NTILE  64
#define XBF_OFF (16u << 20)        // byte offset of x_bf16 inside ws

using short8  = __attribute__((ext_vector_type(8))) short;
using short4v = __attribute__((ext_vector_type(4))) short;
using f32x4   = __attribute__((ext_vector_type(4))) float;

__device__ __forceinline__ short f2bf(float f) {
    __bf16 h = (__bf16)f;                 // pairs into v_cvt_pk_bf16_f32
    return __builtin_bit_cast(short, h);
}

// ---- k0: convert x to bf16 -------------------------------------------------
__global__ __launch_bounds__(256) void cvt_x(
    const float* __restrict__ x, unsigned short* __restrict__ xbf)
{
    const int i = (blockIdx.x * 256 + threadIdx.x) * 8;   // 8 floats/thread
    f32x4 a = *(const f32x4*)(x + i);
    f32x4 b = *(const f32x4*)(x + i + 4);
    short8 h;
    h[0] = f2bf(a[0]); h[1] = f2bf(a[1]); h[2] = f2bf(a[2]); h[3] = f2bf(a[3]);
    h[4] = f2bf(b[0]); h[5] = f2bf(b[1]); h[6] = f2bf(b[2]); h[7] = f2bf(b[3]);
    *(short8*)(xbf + i) = h;
}

// ---- k1: gathered GEMM, weight staged in LDS -------------------------------
__global__ __launch_bounds__(256, 2) void up_gather_gemm(
    const float*          __restrict__ weight,   // [11008, 4096] f32
    const unsigned short* __restrict__ xbf,      // [64, 4096] bf16
    const int*            __restrict__ indices,  // [R]
    float*                __restrict__ ws,       // [KSPLIT, 64, R] partials
    int R)
{
    __shared__ unsigned short wlds[NTILE * KCHUNK];   // 64 KB, XOR-swizzled

    const int t    = threadIdx.x;
    const int lane = t & 63;
    const int wave = t >> 6;       // 0..3 -> 16 batch rows each
    const int nl   = lane & 15;
    const int kg   = lane >> 4;
    const int nb   = blockIdx.x;   // N-tile of 64 gathered rows
    const int kb   = blockIdx.y;   // K-chunk of 512

    // ---- stage weight tile: rows nb*64..+63, cols kb*512..+511, as bf16 ----
    // thread t -> row r = t>>2, col base (t&3)*4, stepping 16 floats.
    {
        const int r  = t >> 2;
        const int c4 = t & 3;
        const int n  = nb * NTILE + r;
        const int row = indices[n < R ? n : R - 1];
        const float* src = weight + (size_t)row * HIDDEN + kb * KCHUNK + c4 * 4;
        char* ldsrow = (char*)wlds + r * (KCHUNK * 2);
        const unsigned int swz = (unsigned int)((r & 7) << 4);
#pragma unroll
        for (int s = 0; s < 32; ++s) {
            f32x4 v = *(const f32x4*)(src + (size_t)s * 16);
            short4v h;
            h[0] = f2bf(v[0]); h[1] = f2bf(v[1]); h[2] = f2bf(v[2]); h[3] = f2bf(v[3]);
            const unsigned int bc = (unsigned int)(c4 * 8 + s * 32);
            *(short4v*)(ldsrow + (bc ^ swz)) = h;
        }
    }
    __syncthreads();

    // ---- K loop: 1 global a-load + 4 swizzled ds_read_b128 + 4 MFMA --------
    const unsigned short* xrow =
        xbf + (size_t)(wave * 16 + nl) * HIDDEN + kb * KCHUNK + kg * 8;

    f32x4 acc0 = {0.f,0.f,0.f,0.f}, acc1 = {0.f,0.f,0.f,0.f};
    f32x4 acc2 = {0.f,0.f,0.f,0.f}, acc3 = {0.f,0.f,0.f,0.f};

#pragma unroll
    for (int ks = 0; ks < KSTEPS; ++ks) {
        short8 a = *(const short8*)(xrow + ks * 32);
#pragma unroll
        for (int nf = 0; nf < 4; ++nf) {
            const int rr = nf * 16 + nl;
            const unsigned int bc =
                (unsigned int)(ks * 64 + kg * 16) ^ (unsigned int)((rr & 7) << 4);
            short8 b = *(const short8*)((const char*)wlds + rr * (KCHUNK * 2) + bc);
            f32x4& acc = nf == 0 ? acc0 : nf == 1 ? acc1 : nf == 2 ? acc2 : acc3;
            acc = __builtin_amdgcn_mfma_f32_16x16x32_bf16(a, b, acc, 0, 0, 0);
        }
    }

    // ---- store partials: C/D col = nl (n), row = kg*4 + r (batch) ----------
    float* part = ws + (size_t)kb * BATCH * R;
    f32x4 accs[4] = {acc0, acc1, acc2, acc3};
#pragma unroll
    for (int nf = 0; nf < 4; ++nf) {
        const int nn = nb * NTILE + nf * 16 + nl;
        if (nn < R) {
#pragma unroll
            for (int r = 0; r < 4; ++r) {
                const int brow = wave * 16 + kg * 4 + r;
                part[(size_t)brow * R + nn] = accs[nf][r];
            }
        }
    }
}

// ---- k2: sum KSPLIT partials ----------------------------------------------
__global__ __launch_bounds__(256) void reduce_partials(
    const float* __restrict__ ws, float* __restrict__ out, int n4, int stride4)
{
    const int i = blockIdx.x * blockDim.x + threadIdx.x;
    if (i >= n4) return;
    const f32x4* w = (const f32x4*)ws;
    f32x4 s = w[i];
#pragma unroll
    for (int kb = 1; kb < KSPLIT; ++kb) {
        f32x4 v = w[(size_t)kb * stride4 + i];
        s[0] += v[0]; s[1] += v[1]; s[2] += v[2]; s[3] += v[3];
    }
    ((f32x4*)out)[i] = s;
}

extern "C" void kernel_launch(void* const* d_in, const int* in_sizes, int n_in,
                              void* d_out, int out_size, void* d_ws, size_t ws_size,
                              hipStream_t stream) {
    const float* x       = (const float*)d_in[0];
    const float* weight  = (const float*)d_in[1];
    const int*   indices = (const int*)d_in[2];
    float*       out     = (float*)d_out;
    float*       ws      = (float*)d_ws;
    unsigned short* xbf  = (unsigned short*)((char*)d_ws + XBF_OFF);

    const int R  = in_sizes[2];                   // 4403
    const int nb = (R + NTILE - 1) / NTILE;       // 69

    cvt_x<<<dim3((BATCH * HIDDEN) / (256 * 8)), dim3(256), 0, stream>>>(x, xbf);
    up_gather_gemm<<<dim3(nb, KSPLIT), dim3(256), 0, stream>>>(weight, xbf, indices, ws, R);

    const int n4 = (BATCH * R) / 4;
    reduce_partials<<<dim3((n4 + 255) / 256), dim3(256), 0, stream>>>(ws, out, n4, n4);
}

// Round 6
// 32.451 us; speedup vs baseline: 3.6286x; 1.0059x over previous
//
#include <hip/hip_runtime.h>
#include <hip/hip_bf16.h>

// out[b,n] = sum_k x[b,k] * weight[indices[n],k]
// M=64, N=4403, K=4096, fp32 in/out.
// R6: R5 ran 2 blocks/CU (64KB LDS) -> staging latency poorly hidden.
//   - NTILE 64->32 (32KB LDS, 4+ blocks/CU, 1104 blocks, 4.3 waves/SIMD)
//   - preload all 16 x-frags (bf16) into 64 VGPRs; inner loop is pure
//     {2 swizzled ds_read_b128 + 2 MFMA} x 16
//   - staging uses b128 LDS writes (<=2-way conflict under XOR swizzle)

#define HIDDEN 4096
#define KSPLIT 8
#define KCHUNK (HIDDEN / KSPLIT)   // 512
#define KSTEPS (KCHUNK / 32)       // 16
#define BATCH  64
#define NTILE  32
#define XBF_OFF (16u << 20)        // byte offset of x_bf16 inside ws

using short8  = __attribute__((ext_vector_type(8))) short;
using f32x4   = __attribute__((ext_vector_type(4))) float;

__device__ __forceinline__ short f2bf(float f) {
    __bf16 h = (__bf16)f;                 // pairs into v_cvt_pk_bf16_f32
    return __builtin_bit_cast(short, h);
}

// ---- k0: convert x to bf16 -------------------------------------------------
__global__ __launch_bounds__(256) void cvt_x(
    const float* __restrict__ x, unsigned short* __restrict__ xbf)
{
    const int i = (blockIdx.x * 256 + threadIdx.x) * 8;
    f32x4 a = *(const f32x4*)(x + i);
    f32x4 b = *(const f32x4*)(x + i + 4);
    short8 h;
    h[0] = f2bf(a[0]); h[1] = f2bf(a[1]); h[2] = f2bf(a[2]); h[3] = f2bf(a[3]);
    h[4] = f2bf(b[0]); h[5] = f2bf(b[1]); h[6] = f2bf(b[2]); h[7] = f2bf(b[3]);
    *(short8*)(xbf + i) = h;
}

// ---- k1: gathered GEMM, weight staged in LDS -------------------------------
__global__ __launch_bounds__(256, 4) void up_gather_gemm(
    const float*          __restrict__ weight,   // [11008, 4096] f32
    const unsigned short* __restrict__ xbf,      // [64, 4096] bf16
    const int*            __restrict__ indices,  // [R]
    float*                __restrict__ ws,       // [KSPLIT, 64, R] partials
    int R)
{
    __shared__ unsigned short wlds[NTILE * KCHUNK];   // 32 KB, XOR-swizzled

    const int t    = threadIdx.x;
    const int lane = t & 63;
    const int wave = t >> 6;       // 0..3 -> M-tile (16 batch rows each)
    const int nl   = lane & 15;
    const int kg   = lane >> 4;
    const int nb   = blockIdx.x;   // N-tile of 32 gathered rows
    const int kb   = blockIdx.y;   // K-chunk of 512

    // ---- stage weight tile: rows nb*32..+31, cols kb*512..+511, bf16 -------
    // 8 threads/row; thread covers cols (t&7)*8 + s*64 (8 f32 -> one b128)
    {
        const int r   = t >> 3;
        const int c   = t & 7;
        const int n   = nb * NTILE + r;
        const int row = indices[n < R ? n : R - 1];
        const float* src = weight + (size_t)row * HIDDEN + kb * KCHUNK + c * 8;
        char* ldsrow = (char*)wlds + r * (KCHUNK * 2);
        const unsigned int swz = (unsigned int)((r & 7) << 4);
#pragma unroll
        for (int s = 0; s < 8; ++s) {
            f32x4 v0 = *(const f32x4*)(src + (size_t)s * 64);
            f32x4 v1 = *(const f32x4*)(src + (size_t)s * 64 + 4);
            short8 h;
            h[0] = f2bf(v0[0]); h[1] = f2bf(v0[1]); h[2] = f2bf(v0[2]); h[3] = f2bf(v0[3]);
            h[4] = f2bf(v1[0]); h[5] = f2bf(v1[1]); h[6] = f2bf(v1[2]); h[7] = f2bf(v1[3]);
            const unsigned int bc = (unsigned int)(c * 16 + s * 128);
            *(short8*)(ldsrow + (bc ^ swz)) = h;
        }
    }

    // ---- preload all a-frags (x bf16) into registers: 16 x short8 ----------
    const unsigned short* xrow =
        xbf + (size_t)(wave * 16 + nl) * HIDDEN + kb * KCHUNK + kg * 8;
    short8 afr[KSTEPS];
#pragma unroll
    for (int ks = 0; ks < KSTEPS; ++ks)
        afr[ks] = *(const short8*)(xrow + ks * 32);

    __syncthreads();

    // ---- K loop: 2 swizzled ds_read_b128 + 2 MFMA per step -----------------
    f32x4 acc0 = {0.f,0.f,0.f,0.f}, acc1 = {0.f,0.f,0.f,0.f};

#pragma unroll
    for (int ks = 0; ks < KSTEPS; ++ks) {
#pragma unroll
        for (int nf = 0; nf < 2; ++nf) {
            const int rr = nf * 16 + nl;
            const unsigned int bc =
                (unsigned int)(ks * 64 + kg * 16) ^ (unsigned int)((rr & 7) << 4);
            short8 b = *(const short8*)((const char*)wlds + rr * (KCHUNK * 2) + bc);
            f32x4& acc = nf == 0 ? acc0 : acc1;
            acc = __builtin_amdgcn_mfma_f32_16x16x32_bf16(afr[ks], b, acc, 0, 0, 0);
        }
    }

    // ---- store partials: C/D col = nl (n), row = kg*4 + r (batch) ----------
    float* part = ws + (size_t)kb * BATCH * R;
    f32x4 accs[2] = {acc0, acc1};
#pragma unroll
    for (int nf = 0; nf < 2; ++nf) {
        const int nn = nb * NTILE + nf * 16 + nl;
        if (nn < R) {
#pragma unroll
            for (int r = 0; r < 4; ++r) {
                const int brow = wave * 16 + kg * 4 + r;
                part[(size_t)brow * R + nn] = accs[nf][r];
            }
        }
    }
}

// ---- k2: sum KSPLIT partials ----------------------------------------------
__global__ __launch_bounds__(256) void reduce_partials(
    const float* __restrict__ ws, float* __restrict__ out, int n4, int stride4)
{
    const int i = blockIdx.x * blockDim.x + threadIdx.x;
    if (i >= n4) return;
    const f32x4* w = (const f32x4*)ws;
    f32x4 s = w[i];
#pragma unroll
    for (int kb = 1; kb < KSPLIT; ++kb) {
        f32x4 v = w[(size_t)kb * stride4 + i];
        s[0] += v[0]; s[1] += v[1]; s[2] += v[2]; s[3] += v[3];
    }
    ((f32x4*)out)[i] = s;
}

extern "C" void kernel_launch(void* const* d_in, const int* in_sizes, int n_in,
                              void* d_out, int out_size, void* d_ws, size_t ws_size,
                              hipStream_t stream) {
    const float* x       = (const float*)d_in[0];
    const float* weight  = (const float*)d_in[1];
    const int*   indices = (const int*)d_in[2];
    float*       out     = (float*)d_out;
    float*       ws      = (float*)d_ws;
    unsigned short* xbf  = (unsigned short*)((char*)d_ws + XBF_OFF);

    const int R  = in_sizes[2];                   // 4403
    const int nb = (R + NTILE - 1) / NTILE;       // 138

    cvt_x<<<dim3((BATCH * HIDDEN) / (256 * 8)), dim3(256), 0, stream>>>(x, xbf);
    up_gather_gemm<<<dim3(nb, KSPLIT), dim3(256), 0, stream>>>(weight, xbf, indices, ws, R);

    const int n4 = (BATCH * R) / 4;
    reduce_partials<<<dim3((n4 + 255) / 256), dim3(256), 0, stream>>>(ws, out, n4, n4);
}